// Round 6
// baseline (289.268 us; speedup 1.0000x reference)
//
#include <hip/hip_runtime.h>
#include <math.h>

typedef __attribute__((ext_vector_type(8)))  short short8;
typedef __attribute__((ext_vector_type(16))) float f32x16;

#define NPLANE 48
#define H 512
#define W 512
#define TH 21
#define OH 492
#define OW 492
#define EPSF 1e-8f

#define STRIDE 168   // LDS row stride in shorts (measured ~conflict-free)
#define SEG_ROWS 84  // 64 output rows + 20 halo

// d_ws layout (bytes) — total ~4.13 MB:
//   [0)        B_corr : 48 * 21 * 4 * 512 bf16 = 4,128,768 B (frag-swizzled)
//   [4128768)  B_ones : 4 * 512 bf16 = 4096 B
#define BONES_HOFF (4128768u / 2)

__device__ inline unsigned short f2bf(float f) {
    unsigned u = __float_as_uint(f);
    return (unsigned short)((u + 0x7FFFu + ((u >> 16) & 1u)) >> 16);
}
__device__ inline float bf2f(unsigned s) {
    return __uint_as_float(s << 16);
}
// Packed RNE f32x2 -> bf16x2; identical rounding to f2bf, 1 VALU op.
__device__ inline unsigned cvtpk(float lo, float hi) {
    unsigned r;
    asm("v_cvt_pk_bf16_f32 %0, %1, %2" : "=v"(r) : "v"(lo), "v"(hi));
    return r;
}

// ---------------------------------------------------------------------------
// K0: template z-norm (/441 folded) -> Toeplitz B fragments (unchanged).
// ---------------------------------------------------------------------------
__global__ void build_b_kernel(const float* __restrict__ tpl,
                               unsigned short* __restrict__ ws16) {
    __shared__ float sm[2];
    const int plane = blockIdx.x;
    const float* t = tpl + plane * 441;
    const int tid = threadIdx.x;
    if (tid < 64) {
        float s = 0.f, s2 = 0.f;
        for (int k = tid; k < 441; k += 64) {
            float x = t[k];
            s += x; s2 += x * x;
        }
#pragma unroll
        for (int o = 32; o >= 1; o >>= 1) {
            s  += __shfl_down(s, o);
            s2 += __shfl_down(s2, o);
        }
        if (tid == 0) {
            float mean = s / 441.f;
            float var = fmaxf(s2 / 441.f - mean * mean, 0.f);
            sm[0] = mean;
            sm[1] = 1.f / ((sqrtf(var) + EPSF) * 441.f);
        }
    }
    __syncthreads();
    const float mean = sm[0], scale = sm[1];

    unsigned short* bc = ws16 + (size_t)plane * 43008;
    for (int i = tid; i < 43008; i += 256) {
        int j = i & 7, lane = (i >> 3) & 63, s = (i >> 9) & 3, u = i >> 11;
        int k = ((lane >> 5) << 3) + j, n = lane & 31;
        int v = 16 * s + k - n;
        float val = (v >= 0 && v < TH) ? (t[u * 21 + v] - mean) * scale : 0.f;
        bc[i] = f2bf(val);
    }
    if (plane == 0) {
        unsigned short* bo = ws16 + BONES_HOFF;
        const unsigned short one = f2bf(1.f);
        for (int i = tid; i < 2048; i += 256) {
            int j = i & 7, lane = (i >> 3) & 63, s = (i >> 9) & 3;
            int k = ((lane >> 5) << 3) + j, n = lane & 31;
            int v = 16 * s + k - n;
            bo[i] = (v >= 0 && v < TH) ? one : (unsigned short)0;
        }
    }
}

// ---------------------------------------------------------------------------
// K1: fused NCC. R6: de-convoy.
// Evidence (R0/R3/R5): duration ~= SUM of pipe times regardless of occupancy
// (12/24/16 waves per CU all ~70-88 us) -> resident blocks are phase-locked:
// identical barrier-delimited phases, started together, re-synced by pipe
// contention. Two coordinated fixes:
//  1. Parity-permuted schedules: even blocks (by (linear>>8)&1, which
//     alternates among a CU's ~6 blocks) run corr in the FIRST barrier
//     window; odd blocks run it in the LAST. Half of each CU's blocks do
//     LDS+MFMA (corr) while the other half do VMEM+VALU (vpass).
//  2. vpass reads GLOBAL f32 (L2-hot; this block staged those exact lines)
//     instead of seg: moves ~4K cyc/block off the contended LDS pipe onto
//     the idle VMEM pipe, and the box sums now use f32 inputs (closer to
//     reference). float2 loads; pairs never straddle W (W even).
// Everything else = R3: 512 thr / 8 waves / one 32x32 tile per wave,
// seg+vbuf = 49.7 KB -> 3 blocks/CU, 4 barriers, rsq epilogue,
// corr unrolled x2 with ping-pong B regs, reg-burst stores.
// ---------------------------------------------------------------------------
__global__ __launch_bounds__(512, 6) void ncc_fused_kernel(
    const float* __restrict__ in, const unsigned short* __restrict__ ws16,
    float* __restrict__ out) {
    __shared__ short seg[SEG_ROWS * STRIDE];   // 28224 B
    __shared__ short vbuf[64 * STRIDE];        // 21504 B  (total 49728 B)

    const int plane = blockIdx.z;
    const int x0 = blockIdx.x * 128;
    const int y0 = blockIdx.y * 64;
    const int tid = threadIdx.x;
    const int lane = tid & 63;
    const int wid = tid >> 6;        // 0..7
    const int tr = wid & 1;          // tile-row (32-row band)
    const int tc = wid >> 1;         // tile-col (32-col band, 0..3)
    const float* src = in + (size_t)plane * H * W;

    // Parity: alternates across the ~6 blocks a CU processes (ids i+256k).
    const int linear = blockIdx.x + 4 * blockIdx.y + 32 * blockIdx.z;
    const int par = (linear >> 8) & 1;

    // ---- stage 84x160 fp32 -> bf16 into LDS (cvt_pk packing) ----
    for (int i = tid; i < SEG_ROWS * 20; i += 512) {
        int row = i / 20, s8 = i - row * 20;
        int gy = y0 + row, gx = x0 + s8 * 8;
        if (gy < H && gx + 7 < W) {
            float4 a = *(const float4*)(src + gy * W + gx);
            float4 b = *(const float4*)(src + gy * W + gx + 4);
            uint4 v;
            v.x = cvtpk(a.x, a.y);
            v.y = cvtpk(a.z, a.w);
            v.z = cvtpk(b.x, b.y);
            v.w = cvtpk(b.z, b.w);
            *(uint4*)&seg[row * STRIDE + s8 * 8] = v;
        } else {
            short8 val;
#pragma unroll
            for (int e = 0; e < 8; ++e) {
                float xv = (gy < H && gx + e < W) ? src[gy * W + gx + e] : 0.f;
                val[e] = (short)f2bf(xv);
            }
            *(short8*)&seg[row * STRIDE + s8 * 8] = val;
        }
    }

    const int m = lane & 31;
    const int half = lane >> 5;
    // Shared row mapping for seg (corr A-reads) AND vbuf (box A-reads).
    const int abase = (tr * 32 + m) * STRIDE + tc * 32 + half * 8;
    const unsigned short* bc = ws16 + (size_t)plane * 43008 + lane * 8;

    // Bones fragments: load once (L2-hot), live in regs to the epilogue.
    const unsigned short* bo16 = ws16 + BONES_HOFF + lane * 8;
    short8 bones[4];
#pragma unroll
    for (int s = 0; s < 4; ++s)
        bones[s] = *(const short8*)(bo16 + s * 512);

    f32x16 acc;
#pragma unroll
    for (int e = 0; e < 16; ++e) acc[e] = 0.f;

    // ---- corr K-loop, unrolled x2 with ping-pong B buffers ----
    auto corr_all = [&]() {
        auto corr_step = [&](int u, short8* bf) {
            short8 af[4];
#pragma unroll
            for (int s = 0; s < 4; ++s)
                af[s] = *(const short8*)&seg[abase + u * STRIDE + s * 16];
#pragma unroll
            for (int s = 0; s < 4; ++s)
                acc = __builtin_amdgcn_mfma_f32_32x32x16_bf16(af[s], bf[s],
                                                              acc, 0, 0, 0);
        };
        short8 bA[4], bB[4];
#pragma unroll
        for (int s = 0; s < 4; ++s)
            bA[s] = *(const short8*)(bc + s * 512);
        for (int u = 0; u < TH - 1; u += 2) {
#pragma unroll
            for (int s = 0; s < 4; ++s)
                bB[s] = *(const short8*)(bc + ((u + 1) * 4 + s) * 512);
            corr_step(u, bA);
#pragma unroll
            for (int s = 0; s < 4; ++s)
                bA[s] = *(const short8*)(bc + ((u + 2) * 4 + s) * 512);
            corr_step(u + 1, bB);
        }
        corr_step(TH - 1, bA);
    };

    // ---- vertical 21-sum pass reading GLOBAL f32 (L2-hot), 320 threads ----
    auto vpassG = [&](bool sq) {
        if (tid < 320) {
            const int q = tid / 80;              // row-quarter 0..3
            const int c2 = (tid - q * 80) * 2;   // col pair
            const int base = q * 16;
            const int gx = x0 + c2;
            const bool colok = (gx + 1) < W;     // W even: pair never straddles
            const float* col = src + gx;
            float s0 = 0.f, s1 = 0.f;
#pragma unroll
            for (int r = 0; r < 20; ++r) {
                int gy = y0 + base + r;
                float a = 0.f, b = 0.f;
                if (gy < H && colok) {
                    float2 v = *(const float2*)(col + (size_t)gy * W);
                    a = v.x; b = v.y;
                }
                if (sq) { s0 = fmaf(a, a, s0); s1 = fmaf(b, b, s1); }
                else    { s0 += a; s1 += b; }
            }
#pragma unroll
            for (int yy = 0; yy < 16; yy += 8) {
                float2 vin[8], vout[8];
#pragma unroll
                for (int r = 0; r < 8; ++r) {
                    int gyi = y0 + base + yy + r + 20;
                    int gyo = y0 + base + yy + r;
                    vin[r] = make_float2(0.f, 0.f);
                    vout[r] = make_float2(0.f, 0.f);
                    if (gyi < H && colok)
                        vin[r] = *(const float2*)(col + (size_t)gyi * W);
                    if (gyo < H && colok)
                        vout[r] = *(const float2*)(col + (size_t)gyo * W);
                }
#pragma unroll
                for (int r = 0; r < 8; ++r) {
                    float a = vin[r].x, b = vin[r].y;
                    if (sq) { s0 = fmaf(a, a, s0); s1 = fmaf(b, b, s1); }
                    else    { s0 += a; s1 += b; }
                    *(unsigned*)&vbuf[(base + yy + r) * STRIDE + c2] =
                        cvtpk(s0, s1);
                    float c = vout[r].x, d = vout[r].y;
                    if (sq) { s0 = fmaf(-c, c, s0); s1 = fmaf(-d, d, s1); }
                    else    { s0 -= c; s1 -= d; }
                }
            }
        }
    };

    f32x16 aS;
    auto boxS = [&]() {
#pragma unroll
        for (int e = 0; e < 16; ++e) aS[e] = 0.f;
#pragma unroll
        for (int s = 0; s < 4; ++s) {
            short8 vf = *(const short8*)&vbuf[abase + s * 16];
            aS = __builtin_amdgcn_mfma_f32_32x32x16_bf16(vf, bones[s], aS,
                                                         0, 0, 0);
        }
    };

    // ---- parity-permuted 4-barrier schedule ----
    __syncthreads();                 // B1: seg ready
    if (!par) { corr_all(); vpassG(false); }
    else      { vpassG(false); }
    __syncthreads();                 // B2: vbuf(sum) ready
    boxS();
    __syncthreads();                 // B3: aS reads done
    if (!par) { vpassG(true); }
    else      { vpassG(true); corr_all(); }
    __syncthreads();                 // B4: vbuf(sq) ready

    // ---- aQ + normalize + tight store burst ----
    f32x16 aQ;
#pragma unroll
    for (int e = 0; e < 16; ++e) aQ[e] = 0.f;
#pragma unroll
    for (int s = 0; s < 4; ++s) {
        short8 qf = *(const short8*)&vbuf[abase + s * 16];
        aQ = __builtin_amdgcn_mfma_f32_32x32x16_bf16(qf, bones[s], aQ,
                                                     0, 0, 0);
    }

    const float invn = 1.f / 441.f;
    float* outp = out + (size_t)plane * OH * OW;
    float vout[16];
#pragma unroll
    for (int r = 0; r < 16; ++r) {
        float mean = aS[r] * invn;
        float msq = aQ[r] * invn;
        float var = fmaf(-mean, mean, msq) + EPSF;
        vout[r] = acc[r] * __builtin_amdgcn_rsqf(var);
    }
    const int gx = x0 + tc * 32 + m;
    if (gx < OW) {
#pragma unroll
        for (int r = 0; r < 16; ++r) {
            int gy = y0 + tr * 32 + (r & 3) + ((r >> 2) << 3) + half * 4;
            if (gy < OH)
                outp[(size_t)gy * OW + gx] = vout[r];
        }
    }
}

extern "C" void kernel_launch(void* const* d_in, const int* in_sizes, int n_in,
                              void* d_out, int out_size, void* d_ws,
                              size_t ws_size, hipStream_t stream) {
    const float* inputs = (const float*)d_in[0];
    const float* tmpl = (const float*)d_in[1];
    float* out = (float*)d_out;
    unsigned short* ws16 = (unsigned short*)d_ws;

    build_b_kernel<<<NPLANE, 256, 0, stream>>>(tmpl, ws16);
    ncc_fused_kernel<<<dim3(4, 8, NPLANE), 512, 0, stream>>>(inputs, ws16, out);
}

// Round 7
// 161.745 us; speedup vs baseline: 1.7884x; 1.7884x over previous
//
#include <hip/hip_runtime.h>
#include <math.h>

typedef __attribute__((ext_vector_type(8)))  short short8;
typedef __attribute__((ext_vector_type(16))) float f32x16;

#define NPLANE 48
#define H 512
#define W 512
#define TH 21
#define OH 492
#define OW 492
#define EPSF 1e-8f

#define STRIDE 168   // LDS row stride in shorts (measured ~conflict-free)
#define SEG_ROWS 84  // 64 output rows + 20 halo

// d_ws layout (bytes) — total ~4.13 MB:
//   [0)        B_corr : 48 * 21 * 4 * 512 bf16 = 4,128,768 B (frag-swizzled)
//   [4128768)  B_ones : 4 * 512 bf16 = 4096 B
#define BONES_HOFF (4128768u / 2)

__device__ inline unsigned short f2bf(float f) {
    unsigned u = __float_as_uint(f);
    return (unsigned short)((u + 0x7FFFu + ((u >> 16) & 1u)) >> 16);
}
// Packed RNE f32x2 -> bf16x2; identical rounding to f2bf, 1 VALU op.
__device__ inline unsigned cvtpk(float lo, float hi) {
    unsigned r;
    asm("v_cvt_pk_bf16_f32 %0, %1, %2" : "=v"(r) : "v"(lo), "v"(hi));
    return r;
}
// Cheap bf16x2 unpack: lo = bits(p<<16), hi = bits(p & 0xffff0000).
__device__ inline float unpk_lo(unsigned p) { return __uint_as_float(p << 16); }
__device__ inline float unpk_hi(unsigned p) {
    return __uint_as_float(p & 0xffff0000u);
}

// ---------------------------------------------------------------------------
// K0: template z-norm (/441 folded) -> Toeplitz B fragments (unchanged).
// ---------------------------------------------------------------------------
__global__ void build_b_kernel(const float* __restrict__ tpl,
                               unsigned short* __restrict__ ws16) {
    __shared__ float sm[2];
    const int plane = blockIdx.x;
    const float* t = tpl + plane * 441;
    const int tid = threadIdx.x;
    if (tid < 64) {
        float s = 0.f, s2 = 0.f;
        for (int k = tid; k < 441; k += 64) {
            float x = t[k];
            s += x; s2 += x * x;
        }
#pragma unroll
        for (int o = 32; o >= 1; o >>= 1) {
            s  += __shfl_down(s, o);
            s2 += __shfl_down(s2, o);
        }
        if (tid == 0) {
            float mean = s / 441.f;
            float var = fmaxf(s2 / 441.f - mean * mean, 0.f);
            sm[0] = mean;
            sm[1] = 1.f / ((sqrtf(var) + EPSF) * 441.f);
        }
    }
    __syncthreads();
    const float mean = sm[0], scale = sm[1];

    unsigned short* bc = ws16 + (size_t)plane * 43008;
    for (int i = tid; i < 43008; i += 256) {
        int j = i & 7, lane = (i >> 3) & 63, s = (i >> 9) & 3, u = i >> 11;
        int k = ((lane >> 5) << 3) + j, n = lane & 31;
        int v = 16 * s + k - n;
        float val = (v >= 0 && v < TH) ? (t[u * 21 + v] - mean) * scale : 0.f;
        bc[i] = f2bf(val);
    }
    if (plane == 0) {
        unsigned short* bo = ws16 + BONES_HOFF;
        const unsigned short one = f2bf(1.f);
        for (int i = tid; i < 2048; i += 256) {
            int j = i & 7, lane = (i >> 3) & 63, s = (i >> 9) & 3;
            int k = ((lane >> 5) << 3) + j, n = lane & 31;
            int v = 16 * s + k - n;
            bo[i] = (v >= 0 && v < TH) ? one : (unsigned short)0;
        }
    }
}

// ---------------------------------------------------------------------------
// K1: fused NCC. R7 = R0 skeleton (best measured: 70.0 us, WRITE 49 MB,
// corr LDS -25% vs R3 via af[6] 2-tile sharing) + pipe trims on the two
// biggest measured consumers (VALU 25 us, HBM 21 us):
//  * cvt_pk staging pack (R1), bit-trick bf16x2 unpack in vpass (2 ops/pair),
//    batched 8-row vpass reads (R1), v_rsq_f32 epilogue (R3).
//  * corr/box MFMA order s-outer/t-inner: acc[t] dep distance 1 -> 2.
//  * B-fragment prefetch distance 2 (named b0/b1/b2, u-unroll 3; 21 = 3x7):
//    B comes from L2 (~200-300 cyc), 1-step ping-pong was borderline.
// Structure: 256 thr / 4 waves, wave = 2 tiles (tr = w&1, tc = w>>1),
// 4-barrier schedule, LDS 49.7 KB -> 3 blocks/CU, direct 64-wide stores.
// ---------------------------------------------------------------------------
__global__ __launch_bounds__(256, 3) void ncc_fused_kernel(
    const float* __restrict__ in, const unsigned short* __restrict__ ws16,
    float* __restrict__ out) {
    __shared__ short seg[SEG_ROWS * STRIDE];   // 28224 B
    __shared__ short vbuf[64 * STRIDE];        // 21504 B  (total 49728 B)

    const int plane = blockIdx.z;
    const int x0 = blockIdx.x * 128;
    const int y0 = blockIdx.y * 64;
    const int tid = threadIdx.x;
    const int lane = tid & 63;
    const int tr = (tid >> 6) & 1;   // tile-row of this wave
    const int tc = tid >> 7;         // tile-col pair of this wave
    const float* src = in + (size_t)plane * H * W;

    // ---- stage 84x160 fp32 -> bf16 into LDS (cvt_pk packing) ----
    for (int i = tid; i < SEG_ROWS * 20; i += 256) {
        int row = i / 20, s8 = i - row * 20;
        int gy = y0 + row, gx = x0 + s8 * 8;
        if (gy < H && gx + 7 < W) {
            float4 a = *(const float4*)(src + gy * W + gx);
            float4 b = *(const float4*)(src + gy * W + gx + 4);
            uint4 v;
            v.x = cvtpk(a.x, a.y);
            v.y = cvtpk(a.z, a.w);
            v.z = cvtpk(b.x, b.y);
            v.w = cvtpk(b.z, b.w);
            *(uint4*)&seg[row * STRIDE + s8 * 8] = v;
        } else {
            short8 val;
#pragma unroll
            for (int e = 0; e < 8; ++e) {
                float xv = (gy < H && gx + e < W) ? src[gy * W + gx + e] : 0.f;
                val[e] = (short)f2bf(xv);
            }
            *(short8*)&seg[row * STRIDE + s8 * 8] = val;
        }
    }
    __syncthreads();

    const int m = lane & 31;
    const int half = lane >> 5;
    const int abase = (tr * 32 + m) * STRIDE + tc * 64 + half * 8;
    const unsigned short* bc = ws16 + (size_t)plane * 43008 + lane * 8;

    f32x16 acc[2];
#pragma unroll
    for (int t = 0; t < 2; ++t)
#pragma unroll
        for (int e = 0; e < 16; ++e) acc[t][e] = 0.f;

    // corr step: af[6] serves both tiles; s-outer/t-inner (dep distance 2).
    auto corr_step = [&](int u, short8* bf) {
        short8 af[6];
#pragma unroll
        for (int g = 0; g < 6; ++g)
            af[g] = *(const short8*)&seg[abase + u * STRIDE + g * 16];
#pragma unroll
        for (int s = 0; s < 4; ++s)
#pragma unroll
            for (int t = 0; t < 2; ++t)
                acc[t] = __builtin_amdgcn_mfma_f32_32x32x16_bf16(
                    af[2 * t + s], bf[s], acc[t], 0, 0, 0);
    };

    auto bload = [&](short8* dst, int u) {
#pragma unroll
        for (int s = 0; s < 4; ++s)
            dst[s] = *(const short8*)(bc + (u * 4 + s) * 512);
    };

    // ---- corr K-loop, unroll x3, named triple-buffer (prefetch dist 2) ----
    short8 b0[4], b1[4], b2[4];
    bload(b0, 0); bload(b1, 1); bload(b2, 2);
    for (int u = 0; u < TH; u += 3) {
        corr_step(u, b0);
        bload(b0, (u + 3 < TH) ? u + 3 : 0);
        corr_step(u + 1, b1);
        bload(b1, (u + 4 < TH) ? u + 4 : 0);
        corr_step(u + 2, b2);
        bload(b2, (u + 5 < TH) ? u + 5 : 0);
    }

    // ---- bones fragments (global, L1/L2-hot) ----
    const unsigned short* bo16 = ws16 + BONES_HOFF + lane * 8;
    short8 bones[4];
#pragma unroll
    for (int s = 0; s < 4; ++s)
        bones[s] = *(const short8*)(bo16 + s * 512);

    // ---- vertical 21-sum pass (batched reads, cheap unpack) ----
    auto vpass = [&](bool sq) {
        if (tid < 160) {
            const int hr = (tid >= 80) ? 32 : 0;
            const int c2 = (tid % 80) * 2;
            float s0 = 0.f, s1 = 0.f;
#pragma unroll
            for (int r = 0; r < 20; ++r) {
                unsigned p = *(const unsigned*)&seg[(hr + r) * STRIDE + c2];
                float a = unpk_lo(p), b = unpk_hi(p);
                if (sq) { s0 = fmaf(a, a, s0); s1 = fmaf(b, b, s1); }
                else    { s0 += a; s1 += b; }
            }
#pragma unroll
            for (int yy = 0; yy < 32; yy += 8) {
                unsigned pin[8], pout[8];
#pragma unroll
                for (int r = 0; r < 8; ++r) {
                    pin[r]  = *(const unsigned*)
                        &seg[(hr + yy + r + 20) * STRIDE + c2];
                    pout[r] = *(const unsigned*)
                        &seg[(hr + yy + r) * STRIDE + c2];
                }
#pragma unroll
                for (int r = 0; r < 8; ++r) {
                    float a = unpk_lo(pin[r]), b = unpk_hi(pin[r]);
                    if (sq) { s0 = fmaf(a, a, s0); s1 = fmaf(b, b, s1); }
                    else    { s0 += a; s1 += b; }
                    *(unsigned*)&vbuf[(hr + yy + r) * STRIDE + c2] =
                        cvtpk(s0, s1);
                    float c = unpk_lo(pout[r]), d = unpk_hi(pout[r]);
                    if (sq) { s0 = fmaf(-c, c, s0); s1 = fmaf(-d, d, s1); }
                    else    { s0 -= c; s1 -= d; }
                }
            }
        }
    };

    // ---- phase schedule (R0-identical, 4 barriers) ----
    vpass(false);
    __syncthreads();

    // aS: box sums via ones-Toeplitz MFMA (s-outer/t-inner).
    f32x16 aS[2];
#pragma unroll
    for (int t = 0; t < 2; ++t)
#pragma unroll
        for (int e = 0; e < 16; ++e) aS[t][e] = 0.f;
#pragma unroll
    for (int s = 0; s < 4; ++s)
#pragma unroll
        for (int t = 0; t < 2; ++t) {
            short8 vf = *(const short8*)&vbuf[abase + (2 * t + s) * 16];
            aS[t] = __builtin_amdgcn_mfma_f32_32x32x16_bf16(vf, bones[s],
                                                            aS[t], 0, 0, 0);
        }
    __syncthreads();

    vpass(true);
    __syncthreads();

    // ---- aQ + normalize (rsq) + store (wave owns 64 contiguous cols) ----
    f32x16 aQ[2];
#pragma unroll
    for (int t = 0; t < 2; ++t)
#pragma unroll
        for (int e = 0; e < 16; ++e) aQ[t][e] = 0.f;
#pragma unroll
    for (int s = 0; s < 4; ++s)
#pragma unroll
        for (int t = 0; t < 2; ++t) {
            short8 qf = *(const short8*)&vbuf[abase + (2 * t + s) * 16];
            aQ[t] = __builtin_amdgcn_mfma_f32_32x32x16_bf16(qf, bones[s],
                                                            aQ[t], 0, 0, 0);
        }

    const float invn = 1.f / 441.f;
    float* outp = out + (size_t)plane * OH * OW;
#pragma unroll
    for (int t = 0; t < 2; ++t) {
        float vout[16];
#pragma unroll
        for (int r = 0; r < 16; ++r) {
            float mean = aS[t][r] * invn;
            float msq = aQ[t][r] * invn;
            float var = fmaf(-mean, mean, msq) + EPSF;
            vout[r] = acc[t][r] * __builtin_amdgcn_rsqf(var);
        }
        const int gx = x0 + tc * 64 + t * 32 + m;
        if (gx < OW) {
#pragma unroll
            for (int r = 0; r < 16; ++r) {
                int gy = y0 + tr * 32 + (r & 3) + ((r >> 2) << 3) + half * 4;
                if (gy < OH)
                    outp[(size_t)gy * OW + gx] = vout[r];
            }
        }
    }
}

extern "C" void kernel_launch(void* const* d_in, const int* in_sizes, int n_in,
                              void* d_out, int out_size, void* d_ws,
                              size_t ws_size, hipStream_t stream) {
    const float* inputs = (const float*)d_in[0];
    const float* tmpl = (const float*)d_in[1];
    float* out = (float*)d_out;
    unsigned short* ws16 = (unsigned short*)d_ws;

    build_b_kernel<<<NPLANE, 256, 0, stream>>>(tmpl, ws16);
    ncc_fused_kernel<<<dim3(4, 8, NPLANE), 256, 0, stream>>>(inputs, ws16, out);
}